// Round 9
// baseline (440.006 us; speedup 1.0000x reference)
//
#include <hip/hip_runtime.h>
#include <math.h>

typedef unsigned short u16;
typedef __attribute__((ext_vector_type(8))) __bf16 bf16x8;
typedef __attribute__((ext_vector_type(4))) float floatx4;

#define T_TOK 4096
#define DD    512
#define FF    2048
#define KH    1024   // K-split half of FF
#define EE    8
#define NSH   2

#define BM 128
#define BN 128
#define BK 32
#define LDK 40   // padded LDS row stride: 80B rows (16B-aligned), 2-way banks (free)
#define BT2 64
#define CAP 4096
#define PADF 0x80000000u
#define NSLOT (2 * T_TOK + EE * BM)

__device__ __forceinline__ float bf2f(u16 v) {
  union { unsigned int u; float f; } c; c.u = ((unsigned int)v) << 16; return c.f;
}
__device__ __forceinline__ u16 f2bf(float f) {
  union { float ff; unsigned int u; } c; c.ff = f;
  unsigned int u = c.u;
  u += 0x7fffu + ((u >> 16) & 1u);   // RNE
  return (u16)(u >> 16);
}
__device__ __forceinline__ float decode(const void* p, size_t idx, int f) {
  return f ? ((const float*)p)[idx] : bf2f(((const u16*)p)[idx]);
}
__device__ __forceinline__ bf16x8 load8(const void* base, size_t idx, int f) {
  if (f) {
    const float* p = (const float*)base + idx;
    float4 a = *(const float4*)p;
    float4 b = *(const float4*)(p + 4);
    union { bf16x8 v; u16 s[8]; } u;
    u.s[0] = f2bf(a.x); u.s[1] = f2bf(a.y); u.s[2] = f2bf(a.z); u.s[3] = f2bf(a.w);
    u.s[4] = f2bf(b.x); u.s[5] = f2bf(b.y); u.s[6] = f2bf(b.z); u.s[7] = f2bf(b.w);
    return u.v;
  }
  return *(const bf16x8*)((const u16*)base + idx);
}

// Probe: classify tensors fp32(1)/bf16(0) via exponent-field stats of first 4096 u16s.
__global__ __launch_bounds__(256) void detect_kernel(
    const void* x, const void* gw, const void* sw1, const void* sw2,
    const void* rw1, const void* rw2, int* flags) {
  __shared__ int cnt;
  const void* ptrs[6] = {x, gw, sw1, sw2, rw1, rw2};
  for (int tnum = 0; tnum < 6; ++tnum) {
    if (threadIdx.x == 0) cnt = 0;
    __syncthreads();
    const u16* p = (const u16*)ptrs[tnum];
    int local = 0;
    for (int i = threadIdx.x; i < 4096; i += 256) {
      unsigned ef = (p[i] >> 7) & 0xFFu;
      if (ef >= 0xE0u) ++local;
    }
    if (local) atomicAdd(&cnt, local);
    __syncthreads();
    if (threadIdx.x == 0) flags[tnum] = (cnt >= 16) ? 1 : 0;
    __syncthreads();
  }
  if (threadIdx.x == 0) {
    flags[6] = flags[0];  // output dtype follows x
    flags[7] = 0;         // ws bf16 buffers
  }
}

// Fused conversion of x + 4 weight tensors into ws bf16 buffers (one launch).
#define CP0 ((size_t)T_TOK * DD)                 // x        2M
#define CP1 (CP0 + (size_t)NSH * FF * DD)        // sw1      4M
#define CP2 (CP1 + (size_t)EE * FF * DD)         // rw1     12M
#define CP3 (CP2 + (size_t)NSH * DD * FF)        // sw2     14M
#define CP4 (CP3 + (size_t)EE * DD * FF)         // rw2     22M
__global__ __launch_bounds__(256) void conv_all(
    const void* __restrict__ x, const void* __restrict__ sw1,
    const void* __restrict__ rw1, const void* __restrict__ sw2,
    const void* __restrict__ rw2, u16* __restrict__ xb, u16* __restrict__ s1b,
    u16* __restrict__ r1b, u16* __restrict__ s2b, u16* __restrict__ r2b,
    const int* __restrict__ flags) {
  size_t i = ((size_t)blockIdx.x * 256 + threadIdx.x) * 8;
  const void* src; u16* dst; int f; size_t base;
  if (i < CP0)      { src = x;   dst = xb;  f = flags[0]; base = 0;   }
  else if (i < CP1) { src = sw1; dst = s1b; f = flags[2]; base = CP0; }
  else if (i < CP2) { src = rw1; dst = r1b; f = flags[4]; base = CP1; }
  else if (i < CP3) { src = sw2; dst = s2b; f = flags[3]; base = CP2; }
  else              { src = rw2; dst = r2b; f = flags[5]; base = CP3; }
  size_t j = i - base;
  *(bf16x8*)(dst + j) = load8(src, j, f);
}

// Router: logits -> softmax(8) -> top-2 -> cw[T][8] + tix[T]
__global__ __launch_bounds__(256) void router_kernel(
    const void* __restrict__ x, const void* __restrict__ gw,
    const u16* __restrict__ gb, const int* __restrict__ flags,
    float* __restrict__ cw, int2* __restrict__ tix) {
  int wave = threadIdx.x >> 6, lane = threadIdx.x & 63;
  int t = blockIdx.x * 4 + wave;
  int fx = flags[0], fg = flags[1];
  float acc[EE];
#pragma unroll
  for (int e = 0; e < EE; ++e) acc[e] = 0.f;
#pragma unroll
  for (int j = 0; j < DD / 64; ++j) {
    int d = lane + j * 64;
    float xv = decode(x, (size_t)t * DD + d, fx);
#pragma unroll
    for (int e = 0; e < EE; ++e)
      acc[e] += xv * decode(gw, (size_t)e * DD + d, fg);
  }
#pragma unroll
  for (int e = 0; e < EE; ++e) {
    float v = acc[e];
#pragma unroll
    for (int off = 32; off > 0; off >>= 1) v += __shfl_xor(v, off, 64);
    acc[e] = v;
  }
  if (lane == 0) {
    float m = -1e30f;
#pragma unroll
    for (int e = 0; e < EE; ++e) {
      acc[e] += bf2f(gb[e]);   // all-zero: dtype-agnostic
      m = fmaxf(m, acc[e]);
    }
    float p[EE], s = 0.f;
#pragma unroll
    for (int e = 0; e < EE; ++e) { p[e] = expf(acc[e] - m); s += p[e]; }
    int i1 = 0;
#pragma unroll
    for (int e = 1; e < EE; ++e) if (p[e] > p[i1]) i1 = e;
    int i2 = (i1 == 0) ? 1 : 0;
#pragma unroll
    for (int e = 0; e < EE; ++e)
      if (e != i1 && p[e] > p[i2]) i2 = e;
    float inv = 1.0f / s;
#pragma unroll
    for (int e = 0; e < EE; ++e)
      cw[t * EE + e] = (e == i1 || e == i2) ? p[e] * inv : 0.0f;
    tix[t] = make_int2(i1, i2);
  }
}

// meta: [0..7]=cnt, [8..15]=pc (padded), [16..23]=row prefix
__global__ void zero_meta(int* meta) {
  if (threadIdx.x < 24) meta[threadIdx.x] = 0;
}
__global__ __launch_bounds__(256) void build_lists(
    const int2* __restrict__ tix, int* __restrict__ meta,
    unsigned* __restrict__ list, int4* __restrict__ srec) {
  int t = blockIdx.x * 256 + threadIdx.x;
  if (t >= T_TOK) return;
  int2 ii = tix[t];
  int p0 = atomicAdd(&meta[ii.x], 1);
  list[(size_t)ii.x * CAP + p0] = (unsigned)t;
  int p1 = atomicAdd(&meta[ii.y], 1);
  list[(size_t)ii.y * CAP + p1] = (unsigned)t;
  srec[t] = make_int4(ii.x, p0, ii.y, p1);
}
__global__ __launch_bounds__(256) void pad_lists(int* meta, unsigned* list) {
  if (threadIdx.x == 0) {
    int off = 0;
    for (int e = 0; e < EE; ++e) {
      int c = meta[e];
      int pc = (c + BM - 1) & ~(BM - 1);
      meta[8 + e] = pc;
      meta[16 + e] = off;
      off += pc;
    }
  }
  __syncthreads();
#pragma unroll
  for (int e = 0; e < EE; ++e) {
    int c = meta[e], pc = meta[8 + e];
    int i = c + threadIdx.x;
    if (i < pc) list[(size_t)e * CAP + i] = PADF;
  }
}

// ---------------- dense 128x128 core (BK=32, proven) ----------------
__device__ __forceinline__ void gemm_core(const void* A, size_t aoff, int fA,
                                          const void* B, size_t boff, int fB,
                                          int K, u16* As, u16* Bs,
                                          floatx4 acc[4][4]) {
  int tid  = threadIdx.x;
  int lane = tid & 63, wave = tid >> 6;
  int wm = (wave >> 1) * 64, wn = (wave & 1) * 64;
  int r = lane & 15, q = lane >> 4;
  int srow = tid >> 2;
  int sc8  = (tid & 3) * 8;
  size_t abase = aoff + (size_t)srow * K + sc8;
  size_t bbase = boff + (size_t)srow * K + sc8;
  const size_t half = (size_t)64 * K;

  for (int k0 = 0; k0 < K; k0 += BK) {
    bf16x8 av0 = load8(A, abase + k0, fA);
    bf16x8 av1 = load8(A, abase + half + k0, fA);
    bf16x8 bv0 = load8(B, bbase + k0, fB);
    bf16x8 bv1 = load8(B, bbase + half + k0, fB);
    __syncthreads();
    *(bf16x8*)(As + srow * LDK + sc8)        = av0;
    *(bf16x8*)(As + (srow + 64) * LDK + sc8) = av1;
    *(bf16x8*)(Bs + srow * LDK + sc8)        = bv0;
    *(bf16x8*)(Bs + (srow + 64) * LDK + sc8) = bv1;
    __syncthreads();

    bf16x8 af[4], bfr[4];
#pragma unroll
    for (int mi = 0; mi < 4; ++mi)
      af[mi] = *(const bf16x8*)(As + (wm + mi * 16 + r) * LDK + q * 8);
#pragma unroll
    for (int ni = 0; ni < 4; ++ni)
      bfr[ni] = *(const bf16x8*)(Bs + (wn + ni * 16 + r) * LDK + q * 8);
#pragma unroll
    for (int mi = 0; mi < 4; ++mi)
#pragma unroll
      for (int ni = 0; ni < 4; ++ni)
        acc[mi][ni] = __builtin_amdgcn_mfma_f32_16x16x32_bf16(
            af[mi], bfr[ni], acc[mi][ni], 0, 0, 0);
  }
}

// dense H = gelu(A·Bᵀ + bias)
__global__ __launch_bounds__(256) void gemm1_gelu(
    const void* __restrict__ A, size_t aoff, const void* __restrict__ B,
    size_t boff, const u16* __restrict__ bias, size_t bioff,
    u16* __restrict__ H, const int* __restrict__ flags, int iA, int iB,
    int N, int K) {
  __shared__ u16 As[BM * LDK];
  __shared__ u16 Bs[BN * LDK];
  int fA = flags[iA], fB = flags[iB];
  floatx4 acc[4][4];
  floatx4 zero = {0.f, 0.f, 0.f, 0.f};
#pragma unroll
  for (int i = 0; i < 4; ++i)
#pragma unroll
    for (int j = 0; j < 4; ++j) acc[i][j] = zero;

  int bm = blockIdx.y * BM, bn = blockIdx.x * BN;
  gemm_core(A, aoff + (size_t)bm * K, fA, B, boff + (size_t)bn * K, fB, K,
            As, Bs, acc);

  int tid = threadIdx.x, wave = tid >> 6, lane = tid & 63;
  int wm = (wave >> 1) * 64, wn = (wave & 1) * 64;
  int r = lane & 15, q = lane >> 4;
#pragma unroll
  for (int mi = 0; mi < 4; ++mi)
#pragma unroll
    for (int ni = 0; ni < 4; ++ni) {
      int col = bn + wn + ni * 16 + r;
      float bv = bf2f(bias[bioff + col]);
#pragma unroll
      for (int rr = 0; rr < 4; ++rr) {
        int row = bm + wm + mi * 16 + q * 4 + rr;
        float v = acc[mi][ni][rr] + bv;
        float g = 0.5f * v * (1.0f + erff(v * 0.70710678118654752f));
        H[(size_t)row * N + col] = f2bf(g);
      }
    }
}

// ---------------- 128x64 core (BK=32, proven) ----------------
__device__ __forceinline__ void core128x64(const u16* ga0, const u16* ga1,
                                           const u16* gb, int K, u16* As,
                                           u16* Bs, floatx4 acc[4][2],
                                           int wm, int wn, int r, int q,
                                           int srow, int sc8) {
  for (int k0 = 0; k0 < K; k0 += BK) {
    bf16x8 av0 = *(const bf16x8*)(ga0 + k0);
    bf16x8 av1 = *(const bf16x8*)(ga1 + k0);
    bf16x8 bv  = *(const bf16x8*)(gb + k0);
    __syncthreads();
    *(bf16x8*)(As + srow * LDK + sc8)        = av0;
    *(bf16x8*)(As + (srow + 64) * LDK + sc8) = av1;
    *(bf16x8*)(Bs + srow * LDK + sc8)        = bv;
    __syncthreads();

    bf16x8 af[4], bfr[2];
#pragma unroll
    for (int mi = 0; mi < 4; ++mi)
      af[mi] = *(const bf16x8*)(As + (wm + mi * 16 + r) * LDK + q * 8);
#pragma unroll
    for (int ni = 0; ni < 2; ++ni)
      bfr[ni] = *(const bf16x8*)(Bs + (wn + ni * 16 + r) * LDK + q * 8);
#pragma unroll
    for (int mi = 0; mi < 4; ++mi)
#pragma unroll
      for (int ni = 0; ni < 2; ++ni)
        acc[mi][ni] = __builtin_amdgcn_mfma_f32_16x16x32_bf16(
            af[mi], bfr[ni], acc[mi][ni], 0, 0, 0);
  }
}

// shared FFN2, K-split: plane (z,ks) = Hsh[:, z*FF+ks*KH ..+KH] · w2[z][:, ks*KH..]ᵀ
// grid (DD/64, T/128, NSH*2); bias added in ks==1 plane only.
__global__ __launch_bounds__(256) void gemm2_shared(
    const u16* __restrict__ Hsh, const u16* __restrict__ w2,
    const u16* __restrict__ bias, float* __restrict__ oacc) {
  int z = blockIdx.z >> 1, ks = blockIdx.z & 1;
  int bm = blockIdx.y * BM, bn = blockIdx.x * BT2;
  __shared__ u16 As[BM * LDK];
  __shared__ u16 Bs[BT2 * LDK];
  floatx4 acc[4][2];
  floatx4 zero = {0.f, 0.f, 0.f, 0.f};
#pragma unroll
  for (int i = 0; i < 4; ++i)
#pragma unroll
    for (int j = 0; j < 2; ++j) acc[i][j] = zero;

  int tid = threadIdx.x, lane = tid & 63, wave = tid >> 6;
  int wm = (wave >> 1) * 64, wn = (wave & 1) * 32;
  int r = lane & 15, q = lane >> 4;
  int srow = tid >> 2, sc8 = (tid & 3) * 8;
  const int ldA = NSH * FF;
  const u16* ga0 = Hsh + (size_t)(bm + srow) * ldA + (size_t)z * FF + ks * KH + sc8;
  const u16* ga1 = ga0 + (size_t)64 * ldA;
  const u16* gb  = w2 + (size_t)z * DD * FF + (size_t)(bn + srow) * FF + ks * KH + sc8;
  core128x64(ga0, ga1, gb, KH, As, Bs, acc, wm, wn, r, q, srow, sc8);

  float* op = oacc + (size_t)blockIdx.z * T_TOK * DD;
#pragma unroll
  for (int mi = 0; mi < 4; ++mi)
#pragma unroll
    for (int rr = 0; rr < 4; ++rr) {
      int row = bm + wm + mi * 16 + q * 4 + rr;
#pragma unroll
      for (int ni = 0; ni < 2; ++ni) {
        int col = bn + wn + ni * 16 + r;
        float bv = ks ? bf2f(bias[(size_t)z * DD + col]) : 0.0f;
        op[(size_t)row * DD + col] = acc[mi][ni][rr] + bv;
      }
    }
}

// routed FFN2 compact, K-split: Ort[ks][ho+slot] = s·(partial_ks + (ks? bias:0))
// grid (DD/64, CAP/128, EE*2)
__global__ __launch_bounds__(256) void gemm2_compact(
    const u16* __restrict__ Hrt, const u16* __restrict__ w2,
    const u16* __restrict__ bias, const unsigned* __restrict__ list,
    const int* __restrict__ meta, const float* __restrict__ cw,
    float* __restrict__ Ort) {
  int e = blockIdx.z >> 1, ks = blockIdx.z & 1;
  int bm = blockIdx.y * BM;
  if (bm >= meta[8 + e]) return;
  int ho = meta[16 + e];
  int bn = blockIdx.x * BT2;
  __shared__ u16 As[BM * LDK];
  __shared__ u16 Bs[BT2 * LDK];
  floatx4 acc[4][2];
  floatx4 zero = {0.f, 0.f, 0.f, 0.f};
#pragma unroll
  for (int i = 0; i < 4; ++i)
#pragma unroll
    for (int j = 0; j < 2; ++j) acc[i][j] = zero;

  int tid = threadIdx.x, lane = tid & 63, wave = tid >> 6;
  int wm = (wave >> 1) * 64, wn = (wave & 1) * 32;
  int r = lane & 15, q = lane >> 4;
  int srow = tid >> 2, sc8 = (tid & 3) * 8;
  const u16* ga0 = Hrt + (size_t)(ho + bm + srow) * FF + ks * KH + sc8;
  const u16* ga1 = ga0 + (size_t)64 * FF;
  const u16* gb  = w2 + (size_t)e * DD * FF + (size_t)(bn + srow) * FF + ks * KH + sc8;
  core128x64(ga0, ga1, gb, KH, As, Bs, acc, wm, wn, r, q, srow, sc8);

  float* op = Ort + (size_t)ks * NSLOT * DD;
#pragma unroll
  for (int mi = 0; mi < 4; ++mi)
#pragma unroll
    for (int rr = 0; rr < 4; ++rr) {
      int slot = bm + wm + mi * 16 + q * 4 + rr;
      unsigned raw = list[(size_t)e * CAP + slot];
      if (raw & PADF) continue;
      float s = cw[raw * EE + e];
#pragma unroll
      for (int ni = 0; ni < 2; ++ni) {
        int col = bn + wn + ni * 16 + r;
        float bv = ks ? bf2f(bias[(size_t)e * DD + col]) : 0.0f;
        op[(size_t)(ho + slot) * DD + col] = s * (acc[mi][ni][rr] + bv);
      }
    }
}

// routed FFN1 gathered (BK=32, proven). grid (FF/128, CAP/128, EE)
__global__ __launch_bounds__(256) void gemm1_gather(
    const u16* __restrict__ xb, const u16* __restrict__ w1,
    const u16* __restrict__ bias, const unsigned* __restrict__ list,
    const int* __restrict__ meta, u16* __restrict__ Hrt) {
  int e = blockIdx.z;
  int bm = blockIdx.y * BM;
  if (bm >= meta[8 + e]) return;
  int ho = meta[16 + e];
  const int K = DD, N = FF;

  __shared__ u16 As[BM * LDK];
  __shared__ u16 Bs[BN * LDK];
  floatx4 acc[4][4];
  floatx4 zero = {0.f, 0.f, 0.f, 0.f};
#pragma unroll
  for (int i = 0; i < 4; ++i)
#pragma unroll
    for (int j = 0; j < 4; ++j) acc[i][j] = zero;

  int bn = blockIdx.x * BN;
  int tid  = threadIdx.x;
  int lane = tid & 63, wave = tid >> 6;
  int wm = (wave >> 1) * 64, wn = (wave & 1) * 64;
  int r = lane & 15, q = lane >> 4;
  int srow = tid >> 2;
  int sc8  = (tid & 3) * 8;
  unsigned t0 = list[(size_t)e * CAP + bm + srow] & 0x7fffffffu;
  unsigned t1 = list[(size_t)e * CAP + bm + srow + 64] & 0x7fffffffu;
  const u16* ga0 = xb + (size_t)t0 * K + sc8;
  const u16* ga1 = xb + (size_t)t1 * K + sc8;
  const u16* gbp = w1 + (size_t)e * FF * DD + (size_t)(bn + srow) * K + sc8;

  for (int k0 = 0; k0 < K; k0 += BK) {
    bf16x8 av0 = *(const bf16x8*)(ga0 + k0);
    bf16x8 av1 = *(const bf16x8*)(ga1 + k0);
    bf16x8 bv0 = *(const bf16x8*)(gbp + k0);
    bf16x8 bv1 = *(const bf16x8*)(gbp + (size_t)64 * K + k0);
    __syncthreads();
    *(bf16x8*)(As + srow * LDK + sc8)        = av0;
    *(bf16x8*)(As + (srow + 64) * LDK + sc8) = av1;
    *(bf16x8*)(Bs + srow * LDK + sc8)        = bv0;
    *(bf16x8*)(Bs + (srow + 64) * LDK + sc8) = bv1;
    __syncthreads();

    bf16x8 af[4], bfr[4];
#pragma unroll
    for (int mi = 0; mi < 4; ++mi)
      af[mi] = *(const bf16x8*)(As + (wm + mi * 16 + r) * LDK + q * 8);
#pragma unroll
    for (int ni = 0; ni < 4; ++ni)
      bfr[ni] = *(const bf16x8*)(Bs + (wn + ni * 16 + r) * LDK + q * 8);
#pragma unroll
    for (int mi = 0; mi < 4; ++mi)
#pragma unroll
      for (int ni = 0; ni < 4; ++ni)
        acc[mi][ni] = __builtin_amdgcn_mfma_f32_16x16x32_bf16(
            af[mi], bfr[ni], acc[mi][ni], 0, 0, 0);
  }

#pragma unroll
  for (int mi = 0; mi < 4; ++mi)
#pragma unroll
    for (int ni = 0; ni < 4; ++ni) {
      int col = bn + wn + ni * 16 + r;
      float bv = bf2f(bias[(size_t)e * FF + col]);
#pragma unroll
      for (int rr = 0; rr < 4; ++rr) {
        int slot = bm + wm + mi * 16 + q * 4 + rr;
        float v = acc[mi][ni][rr] + bv;
        float g = 0.5f * v * (1.0f + erff(v * 0.70710678118654752f));
        Hrt[(size_t)(ho + slot) * N + col] = f2bf(g);
      }
    }
}

// final: out[t] = Σ_{4 oacc planes} + Σ_{2 Ort planes}(g0) + Σ(g1)
typedef struct { u16 a, b, c, d; } u16x4;
__global__ __launch_bounds__(256) void combine_out(
    const float* __restrict__ oacc, const float* __restrict__ Ort,
    const int4* __restrict__ srec, const int* __restrict__ meta,
    void* __restrict__ out, const int* __restrict__ flags) {
  int t  = blockIdx.x * 2 + (threadIdx.x >> 7);
  int c4 = (threadIdx.x & 127) * 4;
  int4 sr = srec[t];
  size_t g0 = (size_t)(meta[16 + sr.x] + sr.y) * DD + c4;
  size_t g1 = (size_t)(meta[16 + sr.z] + sr.w) * DD + c4;
  const size_t PL = (size_t)T_TOK * DD;
  const size_t OP = (size_t)NSLOT * DD;
  size_t tc = (size_t)t * DD + c4;
  float4 r = *(const float4*)(oacc + tc);
  float4 a1 = *(const float4*)(oacc + PL + tc);
  float4 a2 = *(const float4*)(oacc + 2 * PL + tc);
  float4 a3 = *(const float4*)(oacc + 3 * PL + tc);
  float4 u0 = *(const float4*)(Ort + g0);
  float4 u1 = *(const float4*)(Ort + OP + g0);
  float4 v0 = *(const float4*)(Ort + g1);
  float4 v1 = *(const float4*)(Ort + OP + g1);
  float o0 = r.x + a1.x + a2.x + a3.x + u0.x + u1.x + v0.x + v1.x;
  float o1 = r.y + a1.y + a2.y + a3.y + u0.y + u1.y + v0.y + v1.y;
  float o2 = r.z + a1.z + a2.z + a3.z + u0.z + u1.z + v0.z + v1.z;
  float o3 = r.w + a1.w + a2.w + a3.w + u0.w + u1.w + v0.w + v1.w;
  if (flags[6]) {
    *(float4*)((float*)out + tc) = make_float4(o0, o1, o2, o3);
  } else {
    u16x4 h = {f2bf(o0), f2bf(o1), f2bf(o2), f2bf(o3)};
    *(u16x4*)((u16*)out + tc) = h;
  }
}

// ---- fallback-path kernels (dense, unconverted, flag-flex) ----
__global__ __launch_bounds__(256) void gemm2_acc(
    const u16* __restrict__ A, const void* __restrict__ B, size_t boff,
    const u16* __restrict__ bias, size_t bioff, float* __restrict__ outf,
    void* __restrict__ outb, const float* __restrict__ cw,
    const int* __restrict__ flags, int iB, int expert, int accum,
    int row0, int N, int K) {
  __shared__ u16 As[BT2 * LDK];
  __shared__ u16 Bs[BT2 * LDK];
  int fB = flags[iB], fO = flags[6];
  floatx4 acc[2][2];
  floatx4 zero = {0.f, 0.f, 0.f, 0.f};
#pragma unroll
  for (int i = 0; i < 2; ++i)
#pragma unroll
    for (int j = 0; j < 2; ++j) acc[i][j] = zero;
  int bm = blockIdx.y * BT2, bn = blockIdx.x * BT2;
  int tid  = threadIdx.x;
  int lane = tid & 63, wave = tid >> 6;
  int wm = (wave >> 1) * 32, wn = (wave & 1) * 32;
  int r = lane & 15, q = lane >> 4;
  int srow = tid >> 2;
  int sc8  = (tid & 3) * 8;
  size_t abase = (size_t)(bm + srow) * K + sc8;
  size_t bbase = boff + (size_t)(bn + srow) * K + sc8;
  for (int k0 = 0; k0 < K; k0 += BK) {
    bf16x8 av = *(const bf16x8*)(A + abase + k0);
    bf16x8 bv = load8(B, bbase + k0, fB);
    __syncthreads();
    *(bf16x8*)(As + srow * LDK + sc8) = av;
    *(bf16x8*)(Bs + srow * LDK + sc8) = bv;
    __syncthreads();
    bf16x8 af[2], bfr[2];
#pragma unroll
    for (int mi = 0; mi < 2; ++mi)
      af[mi] = *(const bf16x8*)(As + (wm + mi * 16 + r) * LDK + q * 8);
#pragma unroll
    for (int ni = 0; ni < 2; ++ni)
      bfr[ni] = *(const bf16x8*)(Bs + (wn + ni * 16 + r) * LDK + q * 8);
#pragma unroll
    for (int mi = 0; mi < 2; ++mi)
#pragma unroll
      for (int ni = 0; ni < 2; ++ni)
        acc[mi][ni] = __builtin_amdgcn_mfma_f32_16x16x32_bf16(
            af[mi], bfr[ni], acc[mi][ni], 0, 0, 0);
  }
#pragma unroll
  for (int mi = 0; mi < 2; ++mi)
#pragma unroll
    for (int rr = 0; rr < 4; ++rr) {
      int grow = row0 + bm + wm + mi * 16 + q * 4 + rr;
      float s = cw ? cw[grow * EE + expert] : 1.0f;
#pragma unroll
      for (int ni = 0; ni < 2; ++ni) {
        int col = bn + wn + ni * 16 + r;
        float v = acc[mi][ni][rr] + bf2f(bias[bioff + col]);
        size_t idx = (size_t)grow * N + col;
        if (outf) {
          float prev = accum ? outf[idx] : 0.0f;
          outf[idx] = prev + s * v;
        } else if (fO) {
          float* ob = (float*)outb;
          float prev = accum ? ob[idx] : 0.0f;
          ob[idx] = prev + s * v;
        } else {
          u16* ob = (u16*)outb;
          float prev = accum ? bf2f(ob[idx]) : 0.0f;
          ob[idx] = f2bf(prev + s * v);
        }
      }
    }
}

__global__ __launch_bounds__(256) void convert_out(
    const float* __restrict__ acc, void* __restrict__ out,
    const int* __restrict__ flags, int n) {
  int i = blockIdx.x * blockDim.x + threadIdx.x;
  if (i >= n) return;
  if (flags[6]) ((float*)out)[i] = acc[i];
  else ((u16*)out)[i] = f2bf(acc[i]);
}

extern "C" void kernel_launch(void* const* d_in, const int* in_sizes, int n_in,
                              void* d_out, int out_size, void* d_ws, size_t ws_size,
                              hipStream_t stream) {
  (void)in_sizes; (void)n_in; (void)out_size;
  const void* x   = d_in[0];
  const void* gw  = d_in[1];
  const u16*  gb  = (const u16*)d_in[2];
  const void* sw1 = d_in[3];
  const u16*  sb1 = (const u16*)d_in[4];
  const void* sw2 = d_in[5];
  const u16*  sb2 = (const u16*)d_in[6];
  const void* rw1 = d_in[7];
  const u16*  rb1 = (const u16*)d_in[8];
  const void* rw2 = d_in[9];
  const u16*  rb2 = (const u16*)d_in[10];

  const size_t NX   = (size_t)T_TOK * DD;
  const size_t NW1S = (size_t)NSH * FF * DD;
  const size_t NW1R = (size_t)EE * FF * DD;
  const size_t NW2S = (size_t)NSH * DD * FF;
  const size_t NW2R = (size_t)EE * DD * FF;

  // fast-path layout
  size_t off = 0;
  const size_t flO   = off; off += 256;
  const size_t cwO   = off; off += (size_t)T_TOK * EE * 4;
  const size_t tixO  = off; off += (size_t)T_TOK * 8;
  const size_t metaO = off; off += 256;
  const size_t listO = off; off += (size_t)EE * CAP * 4;
  const size_t srecO = off; off += (size_t)T_TOK * 16;
  const size_t accO  = off; off += (size_t)NSH * 2 * T_TOK * DD * 4;  // 4 planes
  const size_t hshO  = off; off += (size_t)T_TOK * NSH * FF * 2;
  const size_t hrtO  = off; off += (size_t)NSLOT * FF * 2;
  const size_t ortO  = off; off += (size_t)2 * NSLOT * DD * 4;        // 2 planes
  const size_t xbO   = off; off += NX * 2;
  const size_t s1O   = off; off += NW1S * 2;
  const size_t r1O   = off; off += NW1R * 2;
  const size_t s2O   = off; off += NW2S * 2;
  const size_t r2O   = off; off += NW2R * 2;
  const int fast = (off <= ws_size) ? 1 : 0;

  char* ws = (char*)d_ws;
  int*   flags = (int*)(ws + flO);
  float* cw    = (float*)(ws + cwO);
  dim3 blk(256);

  detect_kernel<<<1, 256, 0, stream>>>(x, gw, sw1, sw2, rw1, rw2, flags);

  if (fast) {
    int2*     tix  = (int2*)(ws + tixO);
    int*      meta = (int*)(ws + metaO);
    unsigned* list = (unsigned*)(ws + listO);
    int4*     srec = (int4*)(ws + srecO);
    float*    oacc = (float*)(ws + accO);
    u16*      Hsh  = (u16*)(ws + hshO);
    u16*      Hrt  = (u16*)(ws + hrtO);
    float*    Ort  = (float*)(ws + ortO);
    u16*      xb   = (u16*)(ws + xbO);
    u16*      s1b  = (u16*)(ws + s1O);
    u16*      r1b  = (u16*)(ws + r1O);
    u16*      s2b  = (u16*)(ws + s2O);
    u16*      r2b  = (u16*)(ws + r2O);

    conv_all<<<(unsigned)(CP4 / 2048), 256, 0, stream>>>(
        x, sw1, rw1, sw2, rw2, xb, s1b, r1b, s2b, r2b, flags);
    router_kernel<<<T_TOK / 4, 256, 0, stream>>>(x, gw, gb, flags, cw, tix);
    zero_meta<<<1, 64, 0, stream>>>(meta);
    build_lists<<<T_TOK / 256, 256, 0, stream>>>(tix, meta, list, srec);
    pad_lists<<<1, 256, 0, stream>>>(meta, list);

    // shared FFN1: both ns merged (sw1 rows are [NS*F][D] contiguous)
    dim3 g1((NSH * FF) / BN, T_TOK / BM);       // 32 x 32
    gemm1_gelu<<<g1, blk, 0, stream>>>(xb, 0, s1b, 0, sb1, 0, Hsh, flags, 7, 7,
                                       NSH * FF, DD);
    // shared FFN2: K-split into 4 fp32 planes
    dim3 g2(DD / BT2, T_TOK / BM, NSH * 2);     // 8 x 32 x 4
    gemm2_shared<<<g2, blk, 0, stream>>>(Hsh, s2b, sb2, oacc);
    // routed experts
    dim3 gg1(FF / BN, CAP / BM, EE);            // 16 x 32 x 8
    dim3 gg2(DD / BT2, CAP / BM, EE * 2);       // 8 x 32 x 16
    gemm1_gather<<<gg1, blk, 0, stream>>>(xb, r1b, rb1, list, meta, Hrt);
    gemm2_compact<<<gg2, blk, 0, stream>>>(Hrt, r2b, rb2, list, meta, cw, Ort);
    combine_out<<<T_TOK / 2, 256, 0, stream>>>(oacc, Ort, srec, meta, d_out,
                                               flags);
    return;
  }

  // -------- fallback: dense all-FFN path, ws-adaptive --------
  const size_t flB = 256, cwB = (size_t)T_TOK * EE * 4, tixB = (size_t)T_TOK * 8;
  const size_t accB = (size_t)T_TOK * DD * 4;
  static const int tcs[4] = {4096, 2048, 1024, 512};
  int TC = 0, use_f32 = 1;
  for (int i = 0; i < 4; ++i)
    if (flB + cwB + tixB + accB + (size_t)tcs[i] * FF * 2 <= ws_size) { TC = tcs[i]; break; }
  if (!TC) {
    use_f32 = 0;
    for (int i = 0; i < 4; ++i)
      if (flB + cwB + tixB + (size_t)tcs[i] * FF * 2 <= ws_size) { TC = tcs[i]; break; }
  }
  if (!TC) { TC = 512; use_f32 = 0; }

  int2*  tix     = (int2*)(ws + flB + cwB);
  float* out_acc = use_f32 ? (float*)(ws + flB + cwB + tixB) : nullptr;
  u16*   H       = (u16*)(ws + flB + cwB + tixB + (use_f32 ? accB : 0));

  router_kernel<<<T_TOK / 4, 256, 0, stream>>>(x, gw, gb, flags, cw, tix);
  dim3 g1(FF / BN, TC / BM);
  dim3 g2(DD / BT2, TC / BT2);
  const int nchunk = T_TOK / TC;
  for (int f = 0; f < NSH + EE; ++f) {
    const void *w1, *w2; const u16 *b1, *b2; const float* cwp;
    int expert, i1, i2v; size_t w1off, w2off, b1off, b2off;
    if (f < NSH) {
      w1 = sw1; w2 = sw2; b1 = sb1; b2 = sb2;
      w1off = (size_t)f * FF * DD; w2off = (size_t)f * DD * FF;
      b1off = (size_t)f * FF; b2off = (size_t)f * DD;
      cwp = nullptr; expert = 0; i1 = 2; i2v = 3;
    } else {
      int e = f - NSH;
      w1 = rw1; w2 = rw2; b1 = rb1; b2 = rb2;
      w1off = (size_t)e * FF * DD; w2off = (size_t)e * DD * FF;
      b1off = (size_t)e * FF; b2off = (size_t)e * DD;
      cwp = cw; expert = e; i1 = 4; i2v = 5;
    }
    int accum = (f > 0) ? 1 : 0;
    for (int c = 0; c < nchunk; ++c) {
      size_t t0 = (size_t)c * TC;
      gemm1_gelu<<<g1, blk, 0, stream>>>(x, t0 * DD, w1, w1off, b1, b1off, H,
                                         flags, 0, i1, FF, DD);
      gemm2_acc<<<g2, blk, 0, stream>>>(H, w2, w2off, b2, b2off, out_acc,
                                        d_out, cwp, flags, i2v, expert, accum,
                                        (int)t0, DD, FF);
    }
  }
  if (use_f32)
    convert_out<<<(T_TOK * DD) / 256, 256, 0, stream>>>(out_acc, d_out, flags,
                                                        T_TOK * DD);
}